// Round 1
// baseline (3869.994 us; speedup 1.0000x reference)
//
#include <hip/hip_runtime.h>

#define TSTEPS 8192
#define NSEG   2048
#define DTC    0.025f

// Halo decomposition: each block owns C_OWN segments, computes KSTEP steps
// per launch with a KSTEP-wide halo on each side (validity cone shrinks
// 1 segment/side/step).
#define C_OWN  32
#define KSTEP  48
#define NBLK   (NSEG / C_OWN)          // 64 blocks
#define WTH    (C_OWN + 2 * KSTEP)     // 128 threads

__global__ __launch_bounds__(WTH) void hh_phase(
    const float* __restrict__ stim,
    const float* __restrict__ Vin, const float* __restrict__ min_,
    const float* __restrict__ hin, const float* __restrict__ nin,
    float* __restrict__ Vout, float* __restrict__ mout,
    float* __restrict__ hout, float* __restrict__ nout,
    const float* __restrict__ gna_p, const float* __restrict__ gk_p,
    const float* __restrict__ gl_p, const float* __restrict__ gax_p,
    float* __restrict__ out_cur, float* __restrict__ out_volt,
    int t0, int ks)
{
    const int j = threadIdx.x;
    const int b = blockIdx.x;
    const int s = b * C_OWN - KSTEP + j;                 // may be out of range (halo/garbage zone)
    const int sc = s < 0 ? 0 : (s > NSEG - 1 ? NSEG - 1 : s);
    const bool owned = (j >= KSTEP) && (j < KSTEP + C_OWN);  // owned s always in range

    float V = Vin[sc];
    float m = min_[sc];
    float h = hin[sc];
    float n = nin[sc];
    const float gna = gna_p[sc];
    const float gk  = gk_p[sc];
    const float gl  = gl_p[sc];
    const float gax = gax_p[sc];

    __shared__ float Vs[2][WTH];
    const int jm = (j > 0) ? j - 1 : 0;
    const int jp = (j < WTH - 1) ? j + 1 : WTH - 1;
    const bool leftEdge  = (s <= 0);          // sealed end: neighbor = self
    const bool rightEdge = (s >= NSEG - 1);

    for (int k = 0; k < ks; ++k) {
        const int kk = k & 1;
        Vs[kk][j] = V;
        const float is = stim[(size_t)(t0 + k) * NSEG + sc];
        __syncthreads();
        const float Vl = leftEdge  ? V : Vs[kk][jm];
        const float Vr = rightEdge ? V : Vs[kk][jp];

        // rate functions (native exp2-based expf; fp32)
        const float x  = V + 40.0f;
        const float am = 0.1f * x / (1.0f - __expf(-0.1f * x));
        const float bm = 4.0f   * __expf(-(V + 65.0f) * (1.0f / 18.0f));
        const float ah = 0.07f  * __expf(-(V + 65.0f) * 0.05f);
        const float bh = 1.0f / (1.0f + __expf(-(V + 35.0f) * 0.1f));
        const float y  = V + 55.0f;
        const float an = 0.01f * y / (1.0f - __expf(-0.1f * y));
        const float bn = 0.125f * __expf(-(V + 65.0f) * 0.0125f);

        const float m3 = m * m * m;
        const float n2 = n * n;
        const float i_ion = gna * m3 * h * (V - 50.0f)
                          + gk * (n2 * n2) * (V + 77.0f)
                          + gl * (V + 54.387f);
        const float i_ax = gax * (Vl + Vr - 2.0f * V);
        const float dV = i_ax + is - i_ion;        // CM = 1

        if (owned) {
            const size_t o = (size_t)(t0 + k) * NSEG + s;
            out_cur[o]  = dV + i_ion;              // mem_cur = CM*dV + i_ion
            out_volt[o] = V;                       // pre-update V
        }

        V += DTC * dV;
        m += DTC * (am * (1.0f - m) - bm * m);
        h += DTC * (ah * (1.0f - h) - bh * h);
        n += DTC * (an * (1.0f - n) - bn * n);
        // single barrier per step: next iteration writes the other Vs buffer;
        // the barrier above orders writes/reads two iterations apart.
    }

    if (owned) {
        Vout[s] = V; mout[s] = m; hout[s] = h; nout[s] = n;
    }
}

__global__ void hh_init(const float* __restrict__ V0, const float* __restrict__ m0,
                        const float* __restrict__ h0, const float* __restrict__ n0,
                        float* __restrict__ ws)
{
    const int i = blockIdx.x * blockDim.x + threadIdx.x;
    if (i < NSEG) {
        ws[i]            = V0[i];
        ws[NSEG + i]     = m0[i];
        ws[2 * NSEG + i] = h0[i];
        ws[3 * NSEG + i] = n0[i];
    }
}

extern "C" void kernel_launch(void* const* d_in, const int* in_sizes, int n_in,
                              void* d_out, int out_size, void* d_ws, size_t ws_size,
                              hipStream_t stream)
{
    const float* stim = (const float*)d_in[0];
    const float* V0   = (const float*)d_in[1];
    const float* m0   = (const float*)d_in[2];
    const float* h0   = (const float*)d_in[3];
    const float* n0   = (const float*)d_in[4];
    const float* gna  = (const float*)d_in[5];
    const float* gk   = (const float*)d_in[6];
    const float* gl   = (const float*)d_in[7];
    const float* gax  = (const float*)d_in[8];

    float* out      = (float*)d_out;
    float* out_cur  = out;
    float* out_volt = out + (size_t)TSTEPS * NSEG;
    float* tail     = out + 2 * (size_t)TSTEPS * NSEG;  // Vf, mf, hf, nf

    float* ws = (float*)d_ws;   // two state buffers of 4*NSEG floats each

    hipLaunchKernelGGL(hh_init, dim3((NSEG + 255) / 256), dim3(256), 0, stream,
                       V0, m0, h0, n0, ws);

    int p = 0;
    for (int t0 = 0; t0 < TSTEPS; t0 += KSTEP, ++p) {
        const int ks = (TSTEPS - t0) < KSTEP ? (TSTEPS - t0) : KSTEP;
        float* ib = ws + (size_t)(p & 1) * 4 * NSEG;
        float* ob = ws + (size_t)((p + 1) & 1) * 4 * NSEG;
        const bool last = (t0 + ks >= TSTEPS);
        float *Vo, *mo, *ho, *no;
        if (last) {
            Vo = tail;            mo = tail + NSEG;
            ho = tail + 2 * NSEG; no = tail + 3 * NSEG;
        } else {
            Vo = ob;            mo = ob + NSEG;
            ho = ob + 2 * NSEG; no = ob + 3 * NSEG;
        }
        hipLaunchKernelGGL(hh_phase, dim3(NBLK), dim3(WTH), 0, stream,
                           stim,
                           ib, ib + NSEG, ib + 2 * NSEG, ib + 3 * NSEG,
                           Vo, mo, ho, no,
                           gna, gk, gl, gax,
                           out_cur, out_volt, t0, ks);
    }
}

// Round 2
// 2084.214 us; speedup vs baseline: 1.8568x; 1.8568x over previous
//
#include <hip/hip_runtime.h>

#define TSTEPS 8192
#define NSEG   2048
#define DTC    0.025f

// Single-wave halo decomposition: each 64-lane wave owns COWN segments,
// advances KST steps per launch; halo validity cone shrinks 1 lane/side/step.
// Neighbor exchange via wave shuffles -- no LDS, no __syncthreads.
#define KST    28
#define WAVE   64
#define COWN   (WAVE - 2 * KST)   // 8
#define NBLK   (NSEG / COWN)      // 256 blocks, 1 wave each

constexpr double L2E = 1.4426950408889634074;  // log2(e)

// exp2-argument constants, folded in double at compile time.
// e^{a(V+c)} * M  ==  exp2( (a*L2E)*V + (a*c*L2E + log2(M)) )
#define AM_A  ((float)(-0.1 * L2E))
#define AM_B  ((float)(-4.0 * L2E))                    // c=40, M=1
#define BH_B  ((float)(-3.5 * L2E))                    // c=35
#define AN_B  ((float)(-5.5 * L2E))                    // c=55
#define BM_A  ((float)(-L2E / 18.0))
#define BM_B  ((float)(2.0 - 65.0 * L2E / 18.0))       // M=4 -> +2
#define AH_A  ((float)(-0.05 * L2E))
#define AH_B  ((float)(-3.8365012677171206 - 3.25 * L2E))  // log2(0.07) - 65*0.05*L2E
#define BN_A  ((float)(-0.0125 * L2E))
#define BN_B  ((float)(-3.0 - 0.8125 * L2E))           // M=0.125 -> -3

template <int KS>
__global__ __launch_bounds__(WAVE) void hh_phase(
    const float* __restrict__ stim,
    const float* __restrict__ Sin,          // packed V,m,h,n  (4*NSEG)
    float* __restrict__ Sout,               // packed V,m,h,n  (4*NSEG)
    const float* __restrict__ gna_p, const float* __restrict__ gk_p,
    const float* __restrict__ gl_p,  const float* __restrict__ gax_p,
    float* __restrict__ out_cur, float* __restrict__ out_volt,
    int t0, int ksrt)
{
    const int j = threadIdx.x;
    const int s = blockIdx.x * COWN - KST + j;            // may be out of range (halo)
    const int sc = s < 0 ? 0 : (s > NSEG - 1 ? NSEG - 1 : s);
    const bool owned = (j >= KST) && (j < KST + COWN);
    const bool le = (s <= 0);            // sealed end: neighbor = self
    const bool re = (s >= NSEG - 1);

    float V = Sin[sc];
    float m = Sin[NSEG + sc];
    float h = Sin[2 * NSEG + sc];
    float n = Sin[3 * NSEG + sc];
    const float gna = gna_p[sc];
    const float gk  = gk_p[sc];
    const float gl  = gl_p[sc];
    const float gax = gax_p[sc];

    // Prefetch all stim values for this phase into registers (independent,
    // coalesced loads -- all in flight at once).
    float st[KS ? KS : 1];
    if (KS) {
#pragma unroll
        for (int k = 0; k < KS; ++k)
            st[k] = stim[(size_t)(t0 + k) * NSEG + sc];
    }

    const int kmax = KS ? KS : ksrt;
    const long long ob = (long long)t0 * NSEG + s;        // valid when owned

#pragma unroll
    for (int k = 0; k < kmax; ++k) {
        const float is = KS ? st[k] : stim[(size_t)(t0 + k) * NSEG + sc];

        float Vl = __shfl_up(V, 1);
        float Vr = __shfl_down(V, 1);
        Vl = le ? V : Vl;
        Vr = re ? V : Vr;

        // rate functions: each exp = 1 fma + 1 v_exp_f32; divides -> v_rcp_f32
        const float u  = V * AM_A;                         // -0.1*log2e*V (shared)
        const float em = __builtin_amdgcn_exp2f(u + AM_B);
        const float eh = __builtin_amdgcn_exp2f(u + BH_B);
        const float en = __builtin_amdgcn_exp2f(u + AN_B);
        const float am = (0.1f * V + 4.0f)  * __builtin_amdgcn_rcpf(1.0f - em);
        const float bh = __builtin_amdgcn_rcpf(1.0f + eh);
        const float an = (0.01f * V + 0.55f) * __builtin_amdgcn_rcpf(1.0f - en);
        const float bm = __builtin_amdgcn_exp2f(V * BM_A + BM_B);
        const float ah = __builtin_amdgcn_exp2f(V * AH_A + AH_B);
        const float bn = __builtin_amdgcn_exp2f(V * BN_A + BN_B);

        const float m3 = m * m * m;
        const float n2 = n * n;
        const float i_ion = gna * m3 * h * (V - 50.0f)
                          + gk * (n2 * n2) * (V + 77.0f)
                          + gl * (V + 54.387f);
        const float i_ax = gax * (Vl + Vr - 2.0f * V);
        const float dV = i_ax + is - i_ion;                // CM = 1

        if (owned) {
            const long long o = ob + (long long)k * NSEG;
            __builtin_nontemporal_store(dV + i_ion, out_cur + o);  // mem_cur
            __builtin_nontemporal_store(V, out_volt + o);          // pre-update V
        }

        V += DTC * dV;
        m += DTC * (am * (1.0f - m) - bm * m);
        h += DTC * (ah * (1.0f - h) - bh * h);
        n += DTC * (an * (1.0f - n) - bn * n);
    }

    if (owned) {
        Sout[s] = V;
        Sout[NSEG + s] = m;
        Sout[2 * NSEG + s] = h;
        Sout[3 * NSEG + s] = n;
    }
}

__global__ void hh_init(const float* __restrict__ V0, const float* __restrict__ m0,
                        const float* __restrict__ h0, const float* __restrict__ n0,
                        float* __restrict__ ws)
{
    const int i = blockIdx.x * blockDim.x + threadIdx.x;
    if (i < NSEG) {
        ws[i]            = V0[i];
        ws[NSEG + i]     = m0[i];
        ws[2 * NSEG + i] = h0[i];
        ws[3 * NSEG + i] = n0[i];
    }
}

extern "C" void kernel_launch(void* const* d_in, const int* in_sizes, int n_in,
                              void* d_out, int out_size, void* d_ws, size_t ws_size,
                              hipStream_t stream)
{
    const float* stim = (const float*)d_in[0];
    const float* V0   = (const float*)d_in[1];
    const float* m0   = (const float*)d_in[2];
    const float* h0   = (const float*)d_in[3];
    const float* n0   = (const float*)d_in[4];
    const float* gna  = (const float*)d_in[5];
    const float* gk   = (const float*)d_in[6];
    const float* gl   = (const float*)d_in[7];
    const float* gax  = (const float*)d_in[8];

    float* out      = (float*)d_out;
    float* out_cur  = out;
    float* out_volt = out + (size_t)TSTEPS * NSEG;
    float* tail     = out + 2 * (size_t)TSTEPS * NSEG;   // Vf, mf, hf, nf

    float* ws = (float*)d_ws;   // two packed state buffers of 4*NSEG floats

    hipLaunchKernelGGL(hh_init, dim3((NSEG + 255) / 256), dim3(256), 0, stream,
                       V0, m0, h0, n0, ws);

    int p = 0;
    for (int t0 = 0; t0 < TSTEPS; t0 += KST, ++p) {
        const int ks = (TSTEPS - t0) < KST ? (TSTEPS - t0) : KST;
        float* ib = ws + (size_t)(p & 1) * 4 * NSEG;
        float* ob = ws + (size_t)((p + 1) & 1) * 4 * NSEG;
        const bool last = (t0 + ks >= TSTEPS);
        float* So = last ? tail : ob;
        if (ks == KST) {
            hipLaunchKernelGGL((hh_phase<KST>), dim3(NBLK), dim3(WAVE), 0, stream,
                               stim, ib, So, gna, gk, gl, gax,
                               out_cur, out_volt, t0, ks);
        } else {
            hipLaunchKernelGGL((hh_phase<0>), dim3(NBLK), dim3(WAVE), 0, stream,
                               stim, ib, So, gna, gk, gl, gax,
                               out_cur, out_volt, t0, ks);
        }
    }
}